// Round 1
// baseline (2463.235 us; speedup 1.0000x reference)
//
#include <hip/hip_runtime.h>

#define NSENT 4000
#define LSEQ  128
#define VEC   50
#define POS   5
#define EMBD  60      // VEC + 2*POS
#define HIDD  230
#define HSTR  232     // padded channel stride (multiple of 8)
#define NBAG  500
#define NREL  25
#define ESTR  65      // LDS row stride (floats) -> conflict-free strided reads
#define D3    180     // EMBD*3

// ---- Kernel 1: conv_w [HID][EMB][3] -> Wt [k*60+e][c] with c padded to 232 ----
__global__ __launch_bounds__(256) void transpose_w(const float* __restrict__ conv_w,
                                                   float* __restrict__ Wt) {
    int idx = blockIdx.x * 256 + threadIdx.x;
    if (idx >= D3 * HSTR) return;
    int d = idx / HSTR, c = idx - d * HSTR;
    int k = d / EMBD,  e = d - k * EMBD;
    Wt[idx] = (c < HIDD) ? conv_w[(c * EMBD + e) * 3 + k] : 0.f;
}

// ---- Kernel 2: embedding gather + conv1d(k=3, SAME) + maxpool(L) + bias + relu ----
// one block per sentence; thread = (l = tid&127, channel-chunk-half = tid>>7)
__global__ __launch_bounds__(256) void encoder(
    const int*   __restrict__ X,  const int* __restrict__ P1, const int* __restrict__ P2,
    const float* __restrict__ wemb, const float* __restrict__ p1emb, const float* __restrict__ p2emb,
    const float* __restrict__ Wt, const float* __restrict__ conv_b,
    float* __restrict__ H)
{
    __shared__ float embS[130 * ESTR];   // row r holds emb[l=r-1]; rows 0,129 = zero pad
    __shared__ float red[4][8];
    const int n = blockIdx.x, tid = threadIdx.x;

    // zero the two padding rows
    for (int i = tid; i < 2 * ESTR; i += 256) {
        int r = (i < ESTR) ? 0 : 129;
        embS[r * ESTR + (i % ESTR)] = 0.f;
    }
    // gather word/pos embeddings into LDS
    const int* Xr  = X  + n * LSEQ;
    const int* P1r = P1 + n * LSEQ;
    const int* P2r = P2 + n * LSEQ;
    for (int i = tid; i < LSEQ * EMBD; i += 256) {
        int l = i / EMBD, j = i - l * EMBD;
        float v;
        if (j < VEC)            v = wemb[Xr[l] * VEC + j];
        else if (j < VEC + POS) v = p1emb[P1r[l] * POS + (j - VEC)];
        else                    v = p2emb[P2r[l] * POS + (j - VEC - POS)];
        embS[(l + 1) * ESTR + j] = v;
    }
    __syncthreads();

    const int l    = tid & 127;
    const int half = tid >> 7;   // which chunk of the pair this thread handles
    for (int p = 0; p < 15; ++p) {
        const int c0 = (p * 2 + half) * 8;
        float v[8];
        #pragma unroll
        for (int i = 0; i < 8; ++i) v[i] = 0.f;

        if (c0 < HSTR) {
            #pragma unroll
            for (int k = 0; k < 3; ++k) {
                const float* er = embS + (l + k) * ESTR;       // emb[l+k-1][:]
                const float* wr = Wt + (k * EMBD) * HSTR + c0;
                #pragma unroll 4
                for (int e = 0; e < EMBD; ++e) {
                    float ev = er[e];                           // LDS, 2-way (free)
                    float4 wA = *(const float4*)(wr + e * HSTR);     // wave-uniform, L1
                    float4 wB = *(const float4*)(wr + e * HSTR + 4);
                    v[0] = fmaf(ev, wA.x, v[0]);
                    v[1] = fmaf(ev, wA.y, v[1]);
                    v[2] = fmaf(ev, wA.z, v[2]);
                    v[3] = fmaf(ev, wA.w, v[3]);
                    v[4] = fmaf(ev, wB.x, v[4]);
                    v[5] = fmaf(ev, wB.y, v[5]);
                    v[6] = fmaf(ev, wB.z, v[6]);
                    v[7] = fmaf(ev, wB.w, v[7]);
                }
            }
        }
        // max over l: 64-lane shuffle reduce, then combine the 2 waves of this l-group
        #pragma unroll
        for (int i = 0; i < 8; ++i)
            for (int off = 32; off > 0; off >>= 1)
                v[i] = fmaxf(v[i], __shfl_xor(v[i], off));
        if ((tid & 63) == 0) {
            int w = tid >> 6;
            #pragma unroll
            for (int i = 0; i < 8; ++i) red[w][i] = v[i];
        }
        __syncthreads();
        if ((tid & 127) == 0) {
            int w = tid >> 6;  // 0 or 2
            #pragma unroll
            for (int i = 0; i < 8; ++i) {
                int c = c0 + i;
                if (c < HIDD) {
                    float m = fmaxf(red[w][i], red[w + 1][i]);
                    H[n * HSTR + c] = fmaxf(m + conv_b[c], 0.f);
                }
            }
        }
        __syncthreads();
    }
}

// ---- Kernel 3: per-bag softmax attention + relation classifier ----
__global__ __launch_bounds__(256) void attn(
    const float* __restrict__ H, const float* __restrict__ rel_w, const float* __restrict__ rel_b,
    const int* __restrict__ relation, const int* __restrict__ scope,
    float* __restrict__ out)
{
    __shared__ float hS[8][HSTR];
    __shared__ float qS[HSTR];
    __shared__ float logitS[8];
    __shared__ float repS[HSTR];
    const int b = blockIdx.x, tid = threadIdx.x;
    const int start = scope[2 * b];
    int ns = scope[2 * b + 1] - start;
    if (ns > 8) ns = 8;
    const int rel = relation[b];

    if (tid < HSTR) qS[tid] = (tid < HIDD) ? rel_w[rel * HIDD + tid] : 0.f;
    for (int i = tid; i < 8 * HSTR; i += 256) {
        int s = i / HSTR, c = i - s * HSTR;
        hS[s][c] = (s < ns && c < HIDD) ? H[(start + s) * HSTR + c] : 0.f;
    }
    __syncthreads();

    // logits: one 32-lane group per sentence
    {
        int s = tid >> 5, lane = tid & 31;
        float part = 0.f;
        for (int c = lane; c < HIDD; c += 32) part += hS[s][c] * qS[c];
        #pragma unroll
        for (int off = 16; off > 0; off >>= 1) part += __shfl_xor(part, off);
        if (lane == 0) logitS[s] = part;
    }
    __syncthreads();

    // redundant per-thread softmax over <=8 logits
    float a[8];
    float m = -1e30f;
    for (int i = 0; i < ns; ++i) m = fmaxf(m, logitS[i]);
    float den = 0.f;
    #pragma unroll
    for (int i = 0; i < 8; ++i) { a[i] = (i < ns) ? expf(logitS[i] - m) : 0.f; den += a[i]; }
    float inv = 1.f / den;

    if (tid < HIDD) {
        float r = 0.f;
        #pragma unroll
        for (int i = 0; i < 8; ++i) r += a[i] * inv * hS[i][tid];
        repS[tid] = r;
    }
    __syncthreads();

    // classifier: one 8-lane group per relation
    int g = tid >> 3, l8 = tid & 7;
    if (g < NREL) {
        float part = 0.f;
        for (int c = l8; c < HIDD; c += 8) part += repS[c] * rel_w[g * HIDD + c];
        #pragma unroll
        for (int off = 4; off > 0; off >>= 1) part += __shfl_xor(part, off);
        if (l8 == 0) out[b * NREL + g] = part + rel_b[g];
    }
}

extern "C" void kernel_launch(void* const* d_in, const int* in_sizes, int n_in,
                              void* d_out, int out_size, void* d_ws, size_t ws_size,
                              hipStream_t stream) {
    const int*   X        = (const int*)d_in[0];
    const int*   P1       = (const int*)d_in[1];
    const int*   P2       = (const int*)d_in[2];
    // d_in[3] mask, d_in[4] length: unused by the CNN encoder
    const int*   scope    = (const int*)d_in[5];
    const int*   relation = (const int*)d_in[6];
    const float* wemb     = (const float*)d_in[7];
    const float* p1emb    = (const float*)d_in[8];
    const float* p2emb    = (const float*)d_in[9];
    const float* conv_w   = (const float*)d_in[10];
    const float* conv_b   = (const float*)d_in[11];
    const float* rel_w    = (const float*)d_in[12];
    const float* rel_b    = (const float*)d_in[13];

    float* H  = (float*)d_ws;                                        // [4000][232]
    float* Wt = (float*)((char*)d_ws + (size_t)NSENT * HSTR * 4);    // [180][232]

    hipLaunchKernelGGL(transpose_w, dim3((D3 * HSTR + 255) / 256), dim3(256), 0, stream,
                       conv_w, Wt);
    hipLaunchKernelGGL(encoder, dim3(NSENT), dim3(256), 0, stream,
                       X, P1, P2, wemb, p1emb, p2emb, Wt, conv_b, H);
    hipLaunchKernelGGL(attn, dim3(NBAG), dim3(256), 0, stream,
                       H, rel_w, rel_b, relation, scope, (float*)d_out);
}

// Round 2
// 618.544 us; speedup vs baseline: 3.9823x; 3.9823x over previous
//
#include <hip/hip_runtime.h>

#define NSENT 4000
#define LSEQ  128
#define VEC   50
#define POS   5
#define EMBD  60      // VEC + 2*POS
#define HIDD  230
#define HSTR  232     // padded channel stride for H
#define NBAG  500
#define NREL  25
#define NCHUNK 32     // padded 8-channel chunk count (29 real)
#define SLOTS 130     // LDS seq slots: l+1 shift, rows 0/129 = SAME-pad zeros

// ---- Kernel 1: conv_w [HID][EMB][3] -> Wt2 [k][e][chunk][8], zero-padded ----
__global__ __launch_bounds__(256) void transpose_w(const float* __restrict__ conv_w,
                                                   float* __restrict__ Wt2) {
    int idx = blockIdx.x * 256 + threadIdx.x;
    if (idx >= 3 * EMBD * NCHUNK * 8) return;
    int i8 = idx & 7;
    int t  = idx >> 3;
    int chunk = t & 31;
    int u  = t >> 5;          // 0..179
    int e  = u % EMBD;
    int k  = u / EMBD;
    int c  = chunk * 8 + i8;
    Wt2[idx] = (c < HIDD) ? conv_w[(c * EMBD + e) * 3 + k] : 0.f;
}

// ---- Kernel 2: gather + conv1d(k=3,SAME) + maxpool + bias + relu ----
// one block (256 thr = 4 waves) per sentence
// wave w owns channel-chunk (pass*4 + w)  -> wave-uniform weights -> s_load
// lane owns l = {2*lane, 2*lane+1}        -> 64 lanes cover all 128 positions
__global__ __launch_bounds__(256, 4) void encoder(
    const int*   __restrict__ X,  const int* __restrict__ P1, const int* __restrict__ P2,
    const float* __restrict__ wemb, const float* __restrict__ p1emb, const float* __restrict__ p2emb,
    const float* __restrict__ Wt2, const float* __restrict__ conv_b,
    float* __restrict__ H)
{
    __shared__ float embT[EMBD][SLOTS];   // [e][slot], slot = l+1
    const int n = blockIdx.x, tid = threadIdx.x;

    // zero the two pad columns
    for (int e = tid; e < EMBD; e += 256) { embT[e][0] = 0.f; embT[e][SLOTS - 1] = 0.f; }

    // transposed gather of word/pos embeddings
    const int* Xr  = X  + n * LSEQ;
    const int* P1r = P1 + n * LSEQ;
    const int* P2r = P2 + n * LSEQ;
    for (int i = tid; i < LSEQ * 64; i += 256) {
        int l = i >> 6, j = i & 63;
        if (j < EMBD) {
            float v;
            if (j < VEC)            v = wemb[Xr[l] * VEC + j];
            else if (j < VEC + POS) v = p1emb[P1r[l] * POS + (j - VEC)];
            else                    v = p2emb[P2r[l] * POS + (j - VEC - POS)];
            embT[j][l + 1] = v;
        }
    }
    __syncthreads();

    const int lane = tid & 63;
    const int wave = __builtin_amdgcn_readfirstlane(tid >> 6);  // force wave-uniform
    const int i2   = lane * 2;   // slot base: need slots i2 .. i2+3 (emb[l-1..l+2])

    for (int pass = 0; pass < 8; ++pass) {
        const int chunk = pass * 4 + wave;      // uniform per wave
        if (chunk * 8 >= HIDD) continue;        // chunks 29..31 idle (no barriers below)

        float acc0[8], acc1[8];
        #pragma unroll
        for (int i = 0; i < 8; ++i) { acc0[i] = 0.f; acc1[i] = 0.f; }

        const float* wbase = Wt2 + chunk * 8;   // uniform

        for (int e = 0; e < EMBD; ++e) {
            const float* er = &embT[e][i2];
            float2 eA = *(const float2*)(er);       // slots i2, i2+1   (8B aligned)
            float2 eB = *(const float2*)(er + 2);   // slots i2+2, i2+3
            const float evs[4] = { eA.x, eA.y, eB.x, eB.y };
            #pragma unroll
            for (int k = 0; k < 3; ++k) {
                const float* w8 = wbase + (size_t)((k * EMBD + e) * NCHUNK) * 8; // uniform
                float4 wA = *(const float4*)(w8);
                float4 wB = *(const float4*)(w8 + 4);
                const float ea = evs[k];        // l = 2*lane   needs slot 2*lane+k
                const float eb = evs[k + 1];    // l = 2*lane+1 needs slot 2*lane+1+k
                acc0[0] = fmaf(ea, wA.x, acc0[0]);
                acc0[1] = fmaf(ea, wA.y, acc0[1]);
                acc0[2] = fmaf(ea, wA.z, acc0[2]);
                acc0[3] = fmaf(ea, wA.w, acc0[3]);
                acc0[4] = fmaf(ea, wB.x, acc0[4]);
                acc0[5] = fmaf(ea, wB.y, acc0[5]);
                acc0[6] = fmaf(ea, wB.z, acc0[6]);
                acc0[7] = fmaf(ea, wB.w, acc0[7]);
                acc1[0] = fmaf(eb, wA.x, acc1[0]);
                acc1[1] = fmaf(eb, wA.y, acc1[1]);
                acc1[2] = fmaf(eb, wA.z, acc1[2]);
                acc1[3] = fmaf(eb, wA.w, acc1[3]);
                acc1[4] = fmaf(eb, wB.x, acc1[4]);
                acc1[5] = fmaf(eb, wB.y, acc1[5]);
                acc1[6] = fmaf(eb, wB.z, acc1[6]);
                acc1[7] = fmaf(eb, wB.w, acc1[7]);
            }
        }

        // max over this thread's 2 l's, then over all 64 lanes (128 positions)
        #pragma unroll
        for (int i = 0; i < 8; ++i) {
            float m = fmaxf(acc0[i], acc1[i]);
            #pragma unroll
            for (int off = 32; off > 0; off >>= 1)
                m = fmaxf(m, __shfl_xor(m, off));
            if (lane == 0) {
                int c = chunk * 8 + i;
                if (c < HIDD)
                    H[n * HSTR + c] = fmaxf(m + conv_b[c], 0.f);
            }
        }
    }
}

// ---- Kernel 3: per-bag softmax attention + relation classifier ----
__global__ __launch_bounds__(256) void attn(
    const float* __restrict__ H, const float* __restrict__ rel_w, const float* __restrict__ rel_b,
    const int* __restrict__ relation, const int* __restrict__ scope,
    float* __restrict__ out)
{
    __shared__ float hS[8][HSTR];
    __shared__ float qS[HSTR];
    __shared__ float logitS[8];
    __shared__ float repS[HSTR];
    const int b = blockIdx.x, tid = threadIdx.x;
    const int start = scope[2 * b];
    int ns = scope[2 * b + 1] - start;
    if (ns > 8) ns = 8;
    const int rel = relation[b];

    if (tid < HSTR) qS[tid] = (tid < HIDD) ? rel_w[rel * HIDD + tid] : 0.f;
    for (int i = tid; i < 8 * HSTR; i += 256) {
        int s = i / HSTR, c = i - s * HSTR;
        hS[s][c] = (s < ns && c < HIDD) ? H[(start + s) * HSTR + c] : 0.f;
    }
    __syncthreads();

    {
        int s = tid >> 5, lane = tid & 31;
        float part = 0.f;
        for (int c = lane; c < HIDD; c += 32) part += hS[s][c] * qS[c];
        #pragma unroll
        for (int off = 16; off > 0; off >>= 1) part += __shfl_xor(part, off);
        if (lane == 0) logitS[s] = part;
    }
    __syncthreads();

    float a[8];
    float m = -1e30f;
    for (int i = 0; i < ns; ++i) m = fmaxf(m, logitS[i]);
    float den = 0.f;
    #pragma unroll
    for (int i = 0; i < 8; ++i) { a[i] = (i < ns) ? expf(logitS[i] - m) : 0.f; den += a[i]; }
    float inv = 1.f / den;

    if (tid < HIDD) {
        float r = 0.f;
        #pragma unroll
        for (int i = 0; i < 8; ++i) r += a[i] * inv * hS[i][tid];
        repS[tid] = r;
    }
    __syncthreads();

    int g = tid >> 3, l8 = tid & 7;
    if (g < NREL) {
        float part = 0.f;
        for (int c = l8; c < HIDD; c += 8) part += repS[c] * rel_w[g * HIDD + c];
        #pragma unroll
        for (int off = 4; off > 0; off >>= 1) part += __shfl_xor(part, off);
        if (l8 == 0) out[b * NREL + g] = part + rel_b[g];
    }
}

extern "C" void kernel_launch(void* const* d_in, const int* in_sizes, int n_in,
                              void* d_out, int out_size, void* d_ws, size_t ws_size,
                              hipStream_t stream) {
    const int*   X        = (const int*)d_in[0];
    const int*   P1       = (const int*)d_in[1];
    const int*   P2       = (const int*)d_in[2];
    const int*   scope    = (const int*)d_in[5];
    const int*   relation = (const int*)d_in[6];
    const float* wemb     = (const float*)d_in[7];
    const float* p1emb    = (const float*)d_in[8];
    const float* p2emb    = (const float*)d_in[9];
    const float* conv_w   = (const float*)d_in[10];
    const float* conv_b   = (const float*)d_in[11];
    const float* rel_w    = (const float*)d_in[12];
    const float* rel_b    = (const float*)d_in[13];

    float* H   = (float*)d_ws;                                        // [4000][232]
    float* Wt2 = (float*)((char*)d_ws + (size_t)NSENT * HSTR * 4);    // [3][60][32][8]

    const int wtot = 3 * EMBD * NCHUNK * 8;
    hipLaunchKernelGGL(transpose_w, dim3((wtot + 255) / 256), dim3(256), 0, stream,
                       conv_w, Wt2);
    hipLaunchKernelGGL(encoder, dim3(NSENT), dim3(256), 0, stream,
                       X, P1, P2, wemb, p1emb, p2emb, Wt2, conv_b, H);
    hipLaunchKernelGGL(attn, dim3(NBAG), dim3(256), 0, stream,
                       H, rel_w, rel_b, relation, scope, (float*)d_out);
}

// Round 3
// 422.575 us; speedup vs baseline: 5.8291x; 1.4638x over previous
//
#include <hip/hip_runtime.h>

#define NSENT 4000
#define LSEQ  128
#define VEC   50
#define POS   5
#define EMBD  60      // VEC + 2*POS
#define HIDD  230
#define HSTR  232     // padded channel stride for H
#define NBAG  500
#define NREL  25
#define NTILES 15     // ceil(230/16)
#define KSTEPS 6      // K = 192 (3 taps * 64), 6 steps of 32
#define ESTR  72      // LDS row stride in bf16 (144 B -> 4-bank row step, 2-way max)
#define SLOTS 130     // l+1 shift; rows 0/129 are SAME-pad zeros

typedef __attribute__((ext_vector_type(8))) short short8;   // 8 bf16 = 4 VGPRs
typedef __attribute__((ext_vector_type(4))) float f32x4;

__device__ __forceinline__ unsigned short f2bf(float f) {
    union { float f; unsigned u; } v; v.f = f;
    unsigned u = v.u + 0x7FFF + ((v.u >> 16) & 1);   // RNE
    return (unsigned short)(u >> 16);
}

// ---- Kernel 1: conv_w [HID][EMB][3] -> Bfrag[ntile][kstep][lane][8] (bf16) ----
// B-operand layout for mfma_f32_16x16x32_bf16: B[n = lane&15][k = (lane>>4)*8 + j]
// k_lin = kstep*32 + (lane>>4)*8 + j; tap = k_lin>>6; e = k_lin&63
__global__ __launch_bounds__(256) void transpose_w(const float* __restrict__ conv_w,
                                                   unsigned short* __restrict__ Bfrag) {
    int idx = blockIdx.x * 256 + threadIdx.x;
    if (idx >= NTILES * KSTEPS * 64 * 8) return;
    int j    = idx & 7;
    int lane = (idx >> 3) & 63;
    int t    = idx >> 9;
    int ks   = t % KSTEPS;
    int nt   = t / KSTEPS;
    int c    = nt * 16 + (lane & 15);
    int klin = ks * 32 + (lane >> 4) * 8 + j;
    int tap  = klin >> 6;
    int e    = klin & 63;
    float v  = (c < HIDD && e < EMBD) ? conv_w[(c * EMBD + e) * 3 + tap] : 0.f;
    Bfrag[idx] = f2bf(v);
}

// ---- Kernel 2: gather + conv1d(k=3,SAME) via bf16 MFMA + maxpool + bias + relu ----
// one block (4 waves) per sentence; wave w owns N-tiles {4w..4w+3} (wave 3: 3 tiles)
// lane roles: A-frag  A[m=lane&15][k=quad*8+j]  (emb, from LDS)
//             B-frag  B[n=lane&15][k=quad*8+j]  (weights, in VGPRs)
//             C tile  col(n)=lane&15, row(m)=quad*4+reg
__global__ __launch_bounds__(256, 2) void encoder(
    const int*   __restrict__ X,  const int* __restrict__ P1, const int* __restrict__ P2,
    const float* __restrict__ wemb, const float* __restrict__ p1emb, const float* __restrict__ p2emb,
    const unsigned short* __restrict__ Bfrag, const float* __restrict__ conv_b,
    float* __restrict__ H)
{
    __shared__ unsigned short embS[SLOTS * ESTR];   // [slot][e] bf16
    const int n = blockIdx.x, tid = threadIdx.x;
    const int lane = tid & 63;
    const int wave = __builtin_amdgcn_readfirstlane(tid >> 6);
    const int m    = lane & 15;
    const int quad = lane >> 4;

    // ---- load this wave's B fragments (weights) into registers; L2-hot, coalesced
    short8 B[4][KSTEPS];
    bool ntv[4];
    #pragma unroll
    for (int i = 0; i < 4; ++i) {
        int nt = wave * 4 + i;
        ntv[i] = (nt < NTILES);
        if (ntv[i]) {
            #pragma unroll
            for (int ks = 0; ks < KSTEPS; ++ks)
                B[i][ks] = *(const short8*)(Bfrag + ((size_t)(nt * KSTEPS + ks) * 64 + lane) * 8);
        }
    }

    // ---- zero pad rows (slots 0, 129), then transposed bf16 gather into LDS
    for (int i = tid; i < 2 * 64; i += 256) {
        int r = (i < 64) ? 0 : SLOTS - 1;
        embS[r * ESTR + (i & 63)] = 0;
    }
    const int* Xr  = X  + n * LSEQ;
    const int* P1r = P1 + n * LSEQ;
    const int* P2r = P2 + n * LSEQ;
    for (int i = tid; i < LSEQ * 64; i += 256) {
        int l = i >> 6, j = i & 63;
        float v = 0.f;
        if (j < VEC)                 v = wemb[Xr[l] * VEC + j];
        else if (j < VEC + POS)      v = p1emb[P1r[l] * POS + (j - VEC)];
        else if (j < EMBD)           v = p2emb[P2r[l] * POS + (j - VEC - POS)];
        embS[(l + 1) * ESTR + j] = f2bf(v);
    }
    __syncthreads();

    // ---- main loop: 8 M-tiles of 16 positions each
    float maxacc[4][4];
    #pragma unroll
    for (int i = 0; i < 4; ++i)
        #pragma unroll
        for (int r = 0; r < 4; ++r) maxacc[i][r] = -1e30f;

    for (int mt = 0; mt < 8; ++mt) {
        short8 A[KSTEPS];
        #pragma unroll
        for (int ks = 0; ks < KSTEPS; ++ks) {
            int tap = ks >> 1;
            int col = (ks & 1) * 32 + quad * 8;
            int row = mt * 16 + m + tap;            // slot index (l+tap, +1 shift folded)
            A[ks] = *(const short8*)(embS + row * ESTR + col);
        }
        f32x4 acc[4];
        #pragma unroll
        for (int i = 0; i < 4; ++i) acc[i] = (f32x4){0.f, 0.f, 0.f, 0.f};
        #pragma unroll
        for (int ks = 0; ks < KSTEPS; ++ks)
            #pragma unroll
            for (int i = 0; i < 4; ++i)
                if (ntv[i])
                    acc[i] = __builtin_amdgcn_mfma_f32_16x16x32_bf16(A[ks], B[i][ks], acc[i], 0, 0, 0);
        #pragma unroll
        for (int i = 0; i < 4; ++i)
            #pragma unroll
            for (int r = 0; r < 4; ++r)
                maxacc[i][r] = fmaxf(maxacc[i][r], acc[i][r]);
    }

    // ---- reduce: max over regs (4 rows) then quads (xor 16,32) -> 16 rows; bias+relu
    #pragma unroll
    for (int i = 0; i < 4; ++i) {
        if (!ntv[i]) continue;
        float v = fmaxf(fmaxf(maxacc[i][0], maxacc[i][1]), fmaxf(maxacc[i][2], maxacc[i][3]));
        v = fmaxf(v, __shfl_xor(v, 16));
        v = fmaxf(v, __shfl_xor(v, 32));
        if (lane < 16) {
            int c = (wave * 4 + i) * 16 + lane;
            if (c < HIDD)
                H[(size_t)n * HSTR + c] = fmaxf(v + conv_b[c], 0.f);
        }
    }
}

// ---- Kernel 3: per-bag softmax attention + relation classifier ----
__global__ __launch_bounds__(256) void attn(
    const float* __restrict__ H, const float* __restrict__ rel_w, const float* __restrict__ rel_b,
    const int* __restrict__ relation, const int* __restrict__ scope,
    float* __restrict__ out)
{
    __shared__ float hS[8][HSTR];
    __shared__ float qS[HSTR];
    __shared__ float logitS[8];
    __shared__ float repS[HSTR];
    const int b = blockIdx.x, tid = threadIdx.x;
    const int start = scope[2 * b];
    int ns = scope[2 * b + 1] - start;
    if (ns > 8) ns = 8;
    const int rel = relation[b];

    if (tid < HSTR) qS[tid] = (tid < HIDD) ? rel_w[rel * HIDD + tid] : 0.f;
    for (int i = tid; i < 8 * HSTR; i += 256) {
        int s = i / HSTR, c = i - s * HSTR;
        hS[s][c] = (s < ns && c < HIDD) ? H[(size_t)(start + s) * HSTR + c] : 0.f;
    }
    __syncthreads();

    {
        int s = tid >> 5, l32 = tid & 31;
        float part = 0.f;
        for (int c = l32; c < HIDD; c += 32) part += hS[s][c] * qS[c];
        #pragma unroll
        for (int off = 16; off > 0; off >>= 1) part += __shfl_xor(part, off);
        if (l32 == 0) logitS[s] = part;
    }
    __syncthreads();

    float a[8];
    float mx = -1e30f;
    for (int i = 0; i < ns; ++i) mx = fmaxf(mx, logitS[i]);
    float den = 0.f;
    #pragma unroll
    for (int i = 0; i < 8; ++i) { a[i] = (i < ns) ? expf(logitS[i] - mx) : 0.f; den += a[i]; }
    float inv = 1.f / den;

    if (tid < HIDD) {
        float r = 0.f;
        #pragma unroll
        for (int i = 0; i < 8; ++i) r += a[i] * inv * hS[i][tid];
        repS[tid] = r;
    }
    __syncthreads();

    int g = tid >> 3, l8 = tid & 7;
    if (g < NREL) {
        float part = 0.f;
        for (int c = l8; c < HIDD; c += 8) part += repS[c] * rel_w[g * HIDD + c];
        #pragma unroll
        for (int off = 4; off > 0; off >>= 1) part += __shfl_xor(part, off);
        if (l8 == 0) out[b * NREL + g] = part + rel_b[g];
    }
}

extern "C" void kernel_launch(void* const* d_in, const int* in_sizes, int n_in,
                              void* d_out, int out_size, void* d_ws, size_t ws_size,
                              hipStream_t stream) {
    const int*   X        = (const int*)d_in[0];
    const int*   P1       = (const int*)d_in[1];
    const int*   P2       = (const int*)d_in[2];
    const int*   scope    = (const int*)d_in[5];
    const int*   relation = (const int*)d_in[6];
    const float* wemb     = (const float*)d_in[7];
    const float* p1emb    = (const float*)d_in[8];
    const float* p2emb    = (const float*)d_in[9];
    const float* conv_w   = (const float*)d_in[10];
    const float* conv_b   = (const float*)d_in[11];
    const float* rel_w    = (const float*)d_in[12];
    const float* rel_b    = (const float*)d_in[13];

    float* H = (float*)d_ws;                                              // [4000][232] f32
    unsigned short* Bfrag = (unsigned short*)((char*)d_ws + (size_t)NSENT * HSTR * 4);
                                                                          // [15][6][64][8] bf16

    const int btot = NTILES * KSTEPS * 64 * 8;
    hipLaunchKernelGGL(transpose_w, dim3((btot + 255) / 256), dim3(256), 0, stream,
                       conv_w, Bfrag);
    hipLaunchKernelGGL(encoder, dim3(NSENT), dim3(256), 0, stream,
                       X, P1, P2, wemb, p1emb, p2emb, Bfrag, conv_b, H);
    hipLaunchKernelGGL(attn, dim3(NBAG), dim3(256), 0, stream,
                       H, rel_w, rel_b, relation, scope, (float*)d_out);
}

// Round 4
// 187.326 us; speedup vs baseline: 13.1495x; 2.2558x over previous
//
#include <hip/hip_runtime.h>

#define NSENT 4000
#define LSEQ  128
#define VEC   50
#define POS   5
#define EMBD  60      // VEC + 2*POS
#define HIDD  230
#define HSTR  232     // padded channel stride for H
#define NBAG  500
#define NREL  25
#define NTILEP 16     // padded N-tile count (15 real, tile 15 = zeros)
#define KSTEPS 6      // K = 192 (3 taps * 64 e-slots), 6 MFMA K-steps of 32
#define ESTR  72      // LDS row stride in bf16 shorts (144 B)
#define SLOTS 130     // l+1 shift; rows 0/129 are SAME-pad zeros

// e-slot mapping (A and B must agree): 0..49 wemb | 50..54 p1 | 55 zero
//                                      56..60 p2  | 61..63 zero
typedef __attribute__((ext_vector_type(8))) short short8;   // 8 bf16 = 4 VGPRs
typedef __attribute__((ext_vector_type(4))) float f32x4;

__device__ __forceinline__ unsigned short f2bf(float f) {
    union { float f; unsigned u; } v; v.f = f;
    unsigned u = v.u + 0x7FFF + ((v.u >> 16) & 1);   // RNE
    return (unsigned short)(u >> 16);
}

// ---- prep: wemb (f32) -> wembh (bf16), as float2 pairs ----
__global__ __launch_bounds__(256) void conv_wordtab(const float* __restrict__ wemb,
                                                    unsigned short* __restrict__ wembh) {
    int idx = blockIdx.x * 256 + threadIdx.x;
    const int npair = (50002 * VEC) / 2;   // 1,250,050
    if (idx >= npair) return;
    float2 f = ((const float2*)wemb)[idx];
    union { unsigned short s[2]; unsigned u; } o;
    o.s[0] = f2bf(f.x); o.s[1] = f2bf(f.y);
    *(unsigned*)(wembh + idx * 2) = o.u;
}

// ---- prep: p1emb/p2emb [201][5] f32 -> p1h/p2h [201][6] bf16 (col 5 = 0) ----
__global__ __launch_bounds__(256) void conv_postab(const float* __restrict__ p1emb,
                                                   const float* __restrict__ p2emb,
                                                   unsigned short* __restrict__ p1h,
                                                   unsigned short* __restrict__ p2h) {
    int idx = blockIdx.x * 256 + threadIdx.x;
    if (idx >= 2 * 201 * 6) return;
    int t = idx >= 201 * 6;
    int rem = idx - t * 201 * 6;
    int row = rem / 6, col = rem - row * 6;
    const float* src = t ? p2emb : p1emb;
    unsigned short* dst = t ? p2h : p1h;
    dst[rem] = (col < POS) ? f2bf(src[row * POS + col]) : 0;
}

// ---- prep: conv_w [HID][EMB][3] -> Bfrag[ntile][kstep][lane][8] (bf16) ----
// B layout for mfma_f32_16x16x32_bf16: B[n = lane&15][k = (lane>>4)*8 + j]
__global__ __launch_bounds__(256) void transpose_w(const float* __restrict__ conv_w,
                                                   unsigned short* __restrict__ Bfrag) {
    int idx = blockIdx.x * 256 + threadIdx.x;
    if (idx >= NTILEP * KSTEPS * 64 * 8) return;
    int j    = idx & 7;
    int lane = (idx >> 3) & 63;
    int t    = idx >> 9;
    int ks   = t % KSTEPS;
    int nt   = t / KSTEPS;
    int c    = nt * 16 + (lane & 15);
    int klin = ks * 32 + (lane >> 4) * 8 + j;
    int tap  = klin >> 6;
    int e    = klin & 63;
    float v  = 0.f;
    if (c < HIDD) {
        int eidx = -1;
        if (e < 55)      eidx = e;        // 0..49 wemb, 50..54 p1 (e==55 handled below? no: e<55)
        else if (e >= 56 && e < 61) eidx = e - 1;  // 56..60 -> p2 emb idx 55..59
        if (e == 55 || e >= 61) eidx = -1;
        if (eidx >= 0) v = conv_w[(c * EMBD + eidx) * 3 + tap];
    }
    Bfrag[idx] = f2bf(v);
}

// ---- Kernel 2: gather + conv1d(k=3,SAME) via bf16 MFMA + maxpool + bias + relu ----
// one block = 512 thr = 8 waves per sentence; wave w owns N-tiles {2w, 2w+1}
// A-frag A[m=lane&15][k=quad*8+j] from LDS; C tile col=lane&15, row=quad*4+reg
template <bool TBL>
__global__ __launch_bounds__(512, 4) void encoder(
    const int*   __restrict__ X,  const int* __restrict__ P1, const int* __restrict__ P2,
    const float* __restrict__ wemb, const float* __restrict__ p1emb, const float* __restrict__ p2emb,
    const unsigned short* __restrict__ wembh, const unsigned short* __restrict__ p1h,
    const unsigned short* __restrict__ p2h,
    const unsigned short* __restrict__ Bfrag, const float* __restrict__ conv_b,
    float* __restrict__ H)
{
    __shared__ unsigned short embS[SLOTS * ESTR];   // [slot][e] bf16
    __shared__ int xS[LSEQ], p1S[LSEQ], p2S[LSEQ];
    const int n = blockIdx.x, tid = threadIdx.x;
    const int lane = tid & 63;
    const int wave = __builtin_amdgcn_readfirstlane(tid >> 6);
    const int nt0  = wave * 2;
    const int m    = lane & 15;
    const int quad = lane >> 4;

    // ---- this wave's B fragments -> registers (48 VGPRs), issued first
    short8 Bw[2][KSTEPS];
    #pragma unroll
    for (int t = 0; t < 2; ++t)
        #pragma unroll
        for (int ks = 0; ks < KSTEPS; ++ks)
            Bw[t][ks] = *(const short8*)(Bfrag + ((size_t)((nt0 + t) * KSTEPS + ks) * 64 + lane) * 8);

    // ---- stage index rows + zero pad rows
    if (tid < LSEQ)                  xS[tid]        = X [n * LSEQ + tid];
    else if (tid < 2 * LSEQ)         p1S[tid - 128] = P1[n * LSEQ + tid - 128];
    else if (tid < 3 * LSEQ)         p2S[tid - 256] = P2[n * LSEQ + tid - 256];
    else if (tid < 3 * LSEQ + 64) {
        int r = tid & 32 ? SLOTS - 1 : 0;
        int cu = tid & 31;
        *(unsigned*)(embS + r * ESTR + cu * 2) = 0u;
    }
    __syncthreads();

    // ---- pair-gather into LDS: token l, pair pr (2 bf16 = 4 B)
    #pragma unroll
    for (int it = 0; it < (LSEQ * 32) / 512; ++it) {
        int i = tid + it * 512;
        int l = i >> 5, pr = i & 31;
        unsigned val;
        if (TBL) {
            if (pr < 25)       val = *(const unsigned*)(wembh + (size_t)xS[l] * VEC + pr * 2);
            else if (pr < 28)  val = *(const unsigned*)(p1h + p1S[l] * 6 + (pr - 25) * 2);
            else if (pr < 31)  val = *(const unsigned*)(p2h + p2S[l] * 6 + (pr - 28) * 2);
            else               val = 0u;
        } else {
            float a = 0.f, b = 0.f;
            if (pr < 25) {
                float2 f = *(const float2*)(wemb + (size_t)xS[l] * VEC + pr * 2);
                a = f.x; b = f.y;
            } else if (pr < 28) {
                int j0 = (pr - 25) * 2;
                a = p1emb[p1S[l] * POS + j0];
                b = (j0 + 1 < POS) ? p1emb[p1S[l] * POS + j0 + 1] : 0.f;
            } else if (pr < 31) {
                int j0 = (pr - 28) * 2;
                a = p2emb[p2S[l] * POS + j0];
                b = (j0 + 1 < POS) ? p2emb[p2S[l] * POS + j0 + 1] : 0.f;
            }
            union { unsigned short s[2]; unsigned u; } o;
            o.s[0] = f2bf(a); o.s[1] = f2bf(b);
            val = o.u;
        }
        *(unsigned*)(embS + (l + 1) * ESTR + pr * 2) = val;
    }
    __syncthreads();

    // ---- main loop: 8 M-tiles of 16 output positions
    float maxv[2][4];
    #pragma unroll
    for (int t = 0; t < 2; ++t)
        #pragma unroll
        for (int r = 0; r < 4; ++r) maxv[t][r] = -1e30f;

    for (int mt = 0; mt < 8; ++mt) {
        short8 A[KSTEPS];
        #pragma unroll
        for (int ks = 0; ks < KSTEPS; ++ks) {
            int tap = ks >> 1;
            int col = (ks & 1) * 32 + quad * 8;
            int row = mt * 16 + m + tap;            // slot (l+tap), +1 shift folded in
            A[ks] = *(const short8*)(embS + row * ESTR + col);
        }
        f32x4 acc[2];
        #pragma unroll
        for (int t = 0; t < 2; ++t) acc[t] = (f32x4){0.f, 0.f, 0.f, 0.f};
        #pragma unroll
        for (int ks = 0; ks < KSTEPS; ++ks)
            #pragma unroll
            for (int t = 0; t < 2; ++t)
                acc[t] = __builtin_amdgcn_mfma_f32_16x16x32_bf16(A[ks], Bw[t][ks], acc[t], 0, 0, 0);
        #pragma unroll
        for (int t = 0; t < 2; ++t)
            #pragma unroll
            for (int r = 0; r < 4; ++r)
                maxv[t][r] = fmaxf(maxv[t][r], acc[t][r]);
    }

    // ---- reduce rows (4 regs, then quads via xor 16/32) -> bias + relu -> H
    #pragma unroll
    for (int t = 0; t < 2; ++t) {
        float v = fmaxf(fmaxf(maxv[t][0], maxv[t][1]), fmaxf(maxv[t][2], maxv[t][3]));
        v = fmaxf(v, __shfl_xor(v, 16));
        v = fmaxf(v, __shfl_xor(v, 32));
        int c = (nt0 + t) * 16 + lane;
        if (lane < 16 && c < HIDD)
            H[(size_t)n * HSTR + c] = fmaxf(v + conv_b[c], 0.f);
    }
}

// ---- Kernel 3: per-bag softmax attention + relation classifier ----
__global__ __launch_bounds__(256) void attn(
    const float* __restrict__ H, const float* __restrict__ rel_w, const float* __restrict__ rel_b,
    const int* __restrict__ relation, const int* __restrict__ scope,
    float* __restrict__ out)
{
    __shared__ float hS[8][HSTR];
    __shared__ float qS[HSTR];
    __shared__ float logitS[8];
    __shared__ float repS[HSTR];
    const int b = blockIdx.x, tid = threadIdx.x;
    const int start = scope[2 * b];
    int ns = scope[2 * b + 1] - start;
    if (ns > 8) ns = 8;
    const int rel = relation[b];

    if (tid < HSTR) qS[tid] = (tid < HIDD) ? rel_w[rel * HIDD + tid] : 0.f;
    for (int i = tid; i < 8 * HSTR; i += 256) {
        int s = i / HSTR, c = i - s * HSTR;
        hS[s][c] = (s < ns && c < HIDD) ? H[(size_t)(start + s) * HSTR + c] : 0.f;
    }
    __syncthreads();

    {
        int s = tid >> 5, l32 = tid & 31;
        float part = 0.f;
        for (int c = l32; c < HIDD; c += 32) part += hS[s][c] * qS[c];
        #pragma unroll
        for (int off = 16; off > 0; off >>= 1) part += __shfl_xor(part, off);
        if (l32 == 0) logitS[s] = part;
    }
    __syncthreads();

    float a[8];
    float mx = -1e30f;
    for (int i = 0; i < ns; ++i) mx = fmaxf(mx, logitS[i]);
    float den = 0.f;
    #pragma unroll
    for (int i = 0; i < 8; ++i) { a[i] = (i < ns) ? expf(logitS[i] - mx) : 0.f; den += a[i]; }
    float inv = 1.f / den;

    if (tid < HIDD) {
        float r = 0.f;
        #pragma unroll
        for (int i = 0; i < 8; ++i) r += a[i] * inv * hS[i][tid];
        repS[tid] = r;
    }
    __syncthreads();

    int g = tid >> 3, l8 = tid & 7;
    if (g < NREL) {
        float part = 0.f;
        for (int c = l8; c < HIDD; c += 8) part += repS[c] * rel_w[g * HIDD + c];
        #pragma unroll
        for (int off = 4; off > 0; off >>= 1) part += __shfl_xor(part, off);
        if (l8 == 0) out[b * NREL + g] = part + rel_b[g];
    }
}

extern "C" void kernel_launch(void* const* d_in, const int* in_sizes, int n_in,
                              void* d_out, int out_size, void* d_ws, size_t ws_size,
                              hipStream_t stream) {
    const int*   X        = (const int*)d_in[0];
    const int*   P1       = (const int*)d_in[1];
    const int*   P2       = (const int*)d_in[2];
    const int*   scope    = (const int*)d_in[5];
    const int*   relation = (const int*)d_in[6];
    const float* wemb     = (const float*)d_in[7];
    const float* p1emb    = (const float*)d_in[8];
    const float* p2emb    = (const float*)d_in[9];
    const float* conv_w   = (const float*)d_in[10];
    const float* conv_b   = (const float*)d_in[11];
    const float* rel_w    = (const float*)d_in[12];
    const float* rel_b    = (const float*)d_in[13];

    // workspace layout
    char* ws = (char*)d_ws;
    float* H = (float*)ws;                                   // 4000*232*4   = 3,712,000
    size_t off = (size_t)NSENT * HSTR * 4;
    unsigned short* Bfrag = (unsigned short*)(ws + off);     // 16*6*64*8*2  =    98,304
    off += (size_t)NTILEP * KSTEPS * 64 * 8 * 2;
    unsigned short* wembh = (unsigned short*)(ws + off);     // 50002*50*2   = 5,000,200
    size_t off_w = off; off += (size_t)50002 * VEC * 2;
    unsigned short* p1h = (unsigned short*)(ws + off);       // 201*6*2
    off += 201 * 6 * 2;
    unsigned short* p2h = (unsigned short*)(ws + off);
    off += 201 * 6 * 2;
    const bool use_tbl = (ws_size >= off);
    (void)off_w;

    if (use_tbl) {
        const int npair = (50002 * VEC) / 2;
        hipLaunchKernelGGL(conv_wordtab, dim3((npair + 255) / 256), dim3(256), 0, stream,
                           wemb, wembh);
        hipLaunchKernelGGL(conv_postab, dim3((2 * 201 * 6 + 255) / 256), dim3(256), 0, stream,
                           p1emb, p2emb, p1h, p2h);
    }
    const int btot = NTILEP * KSTEPS * 64 * 8;
    hipLaunchKernelGGL(transpose_w, dim3((btot + 255) / 256), dim3(256), 0, stream,
                       conv_w, Bfrag);
    if (use_tbl)
        hipLaunchKernelGGL((encoder<true>), dim3(NSENT), dim3(512), 0, stream,
                           X, P1, P2, wemb, p1emb, p2emb, wembh, p1h, p2h, Bfrag, conv_b, H);
    else
        hipLaunchKernelGGL((encoder<false>), dim3(NSENT), dim3(512), 0, stream,
                           X, P1, P2, wemb, p1emb, p2emb, wembh, p1h, p2h, Bfrag, conv_b, H);
    hipLaunchKernelGGL(attn, dim3(NBAG), dim3(256), 0, stream,
                       H, rel_w, rel_b, relation, scope, (float*)d_out);
}